// Round 2
// baseline (696.285 us; speedup 1.0000x reference)
//
#include <hip/hip_runtime.h>
#include <math.h>

// Problem constants (fixed by the reference setup)
constexpr int B_  = 16;
constexpr int CH  = 512;
constexpr int HW  = 128 * 128;   // 16384
constexpr int C_  = 16;          // selected classes
constexpr int G_  = 32;          // channel groups = CH / C_
constexpr int NP  = (C_ * (C_ - 1)) / 2;  // 120 off-diagonal upper pairs
constexpr int NSPLIT = 4;        // HW-axis split per (b,g)
constexpr int HWS = HW / NSPLIT; // 4096 points per split

// ---------------------------------------------------------------------------
// Kernel 0: per selected class, top-G channels of |w| in descending order
// (stable tie-break by smaller index, matching jnp.argsort(-w_abs)), plus
// sigmoid(|w|) weights. One wave per class; 512 values live in registers
// (8 per lane); 32 rounds of 64-lane butterfly argmax.
// Output layout (group-major, matching perm = ch_ids.reshape(G*C)):
//   perm_tbl[k*C + j] = idx[sel[j]][k],  wgh_tbl[k*C + j] = sigmoid(|w|)
// ---------------------------------------------------------------------------
__global__ __launch_bounds__(64)
void topk_kernel(const float* __restrict__ w, const int* __restrict__ sel,
                 int* __restrict__ perm_tbl, float* __restrict__ wgh_tbl) {
  const int j    = blockIdx.x;    // class slot 0..C_-1
  const int lane = threadIdx.x;   // 0..63
  const float* wr = w + (size_t)sel[j] * CH;

  float vals[8];
#pragma unroll
  for (int i = 0; i < 8; ++i) vals[i] = fabsf(wr[lane * 8 + i]);

  for (int k = 0; k < G_; ++k) {
    float bv = vals[0];
    int bloc = 0;
#pragma unroll
    for (int i = 1; i < 8; ++i)
      if (vals[i] > bv) { bv = vals[i]; bloc = i; }
    int bi = lane * 8 + bloc;

#pragma unroll
    for (int m = 1; m < 64; m <<= 1) {
      float ov = __shfl_xor(bv, m);
      int   oi = __shfl_xor(bi, m);
      if (ov > bv || (ov == bv && oi < bi)) { bv = ov; bi = oi; }
    }

    if (lane == 0) {
      perm_tbl[k * C_ + j] = bi;
      wgh_tbl [k * C_ + j] = 1.0f / (1.0f + expf(-bv));
    }

    if ((bi >> 3) == lane) {
#pragma unroll
      for (int i = 0; i < 8; ++i)
        if ((bi & 7) == i) vals[i] = -1.0f;
    }
  }
}

// ---------------------------------------------------------------------------
// Kernel 1: one block per (b, g, split). 256 threads stream HW/4 points of
// the 16 selected channels (float2, coalesced) and accumulate the 120
// upper-triangular pair dot-product PARTIALS in registers. No abs here —
// abs is only valid after the full-HW sum (kernel 2).
// Block id = (b*G + g)*NSPLIT + split  (split inner → same-b blocks
// co-resident for LLC reuse of duplicated perm channels).
// ---------------------------------------------------------------------------
__global__ __launch_bounds__(256, 2)
void gram_part_kernel(const float* __restrict__ x,
                      const int* __restrict__ perm_tbl,
                      float* __restrict__ part) {
  const int bid   = blockIdx.x;
  const int split = bid & (NSPLIT - 1);
  const int bg    = bid >> 2;      // / NSPLIT
  const int b     = bg >> 5;       // / G_
  const int g     = bg & (G_ - 1);
  const int t     = threadIdx.x;

  __shared__ int s_ch[C_];
  if (t < C_) s_ch[t] = perm_tbl[g * C_ + t];
  __syncthreads();

  const float* bb = x + (size_t)b * ((size_t)CH * HW) + split * HWS;
  int off[C_];
#pragma unroll
  for (int c = 0; c < C_; ++c) off[c] = s_ch[c] * HW;

  float acc[NP];
#pragma unroll
  for (int i = 0; i < NP; ++i) acc[i] = 0.0f;

  // HWS / (256 threads * 2 floats) = 8 iterations
  for (int it = 0; it < HWS / (256 * 2); ++it) {
    const int h = (it * 256 + t) * 2;
    float2 v[C_];
#pragma unroll
    for (int c = 0; c < C_; ++c)
      v[c] = *(const float2*)(bb + off[c] + h);

    int p = 0;
#pragma unroll
    for (int c = 0; c < C_; ++c) {
#pragma unroll
      for (int d = c + 1; d < C_; ++d) {
        acc[p] = fmaf(v[c].x, v[d].x, acc[p]);
        acc[p] = fmaf(v[c].y, v[d].y, acc[p]);
        ++p;
      }
    }
  }

  // 64-lane butterfly reduce each pair accumulator
  const int lane = t & 63;
  const int wv   = t >> 6;
#pragma unroll
  for (int i = 0; i < NP; ++i) {
    float a = acc[i];
#pragma unroll
    for (int m = 1; m < 64; m <<= 1) a += __shfl_xor(a, m);
    acc[i] = a;
  }

  __shared__ float s_part[4][NP];
  if (lane == 0) {
#pragma unroll
    for (int i = 0; i < NP; ++i) s_part[wv][i] = acc[i];
  }
  __syncthreads();

  if (t < NP) {
    part[(size_t)bid * NP + t] =
        s_part[0][t] + s_part[1][t] + s_part[2][t] + s_part[3][t];
  }
}

// ---------------------------------------------------------------------------
// Kernel 2: one block per (b, g). Sum the 4 split partials per pair, apply
// |.| * w_c * w_d, block-reduce, one atomicAdd per block.
// ---------------------------------------------------------------------------
__global__ __launch_bounds__(128)
void finalize_kernel(const float* __restrict__ part,
                     const float* __restrict__ wgh_tbl,
                     float* __restrict__ out) {
  const int bg = blockIdx.x;       // 0 .. B_*G_-1
  const int g  = bg & (G_ - 1);
  const int t  = threadIdx.x;

  float v = 0.0f;
  if (t < NP) {
    const float* p = part + (size_t)bg * NSPLIT * NP + t;
    float s = p[0] + p[NP] + p[2 * NP] + p[3 * NP];
    // decode linear pair index t -> (c, d), c < d
    int cc = 0, rem = t;
    while (rem >= (C_ - 1) - cc) { rem -= (C_ - 1) - cc; ++cc; }
    int dd = cc + 1 + rem;
    v = fabsf(s) * wgh_tbl[g * C_ + cc] * wgh_tbl[g * C_ + dd];
  }

  __shared__ float s_red[128];
  s_red[t] = v;
  __syncthreads();
  for (int st = 64; st > 0; st >>= 1) {
    if (t < st) s_red[t] += s_red[t + st];
    __syncthreads();
  }

  if (t == 0) {
    // loss = sum_{b,g,c<d} w_c w_d |dot| / (NP * (HW-1) * B)
    constexpr float SCALE = 1.0f / (120.0f * 16383.0f * 16.0f);
    atomicAdd(out, s_red[0] * SCALE);
  }
}

extern "C" void kernel_launch(void* const* d_in, const int* in_sizes, int n_in,
                              void* d_out, int out_size, void* d_ws, size_t ws_size,
                              hipStream_t stream) {
  const float* x   = (const float*)d_in[0];
  const float* w   = (const float*)d_in[1];
  const int*   sel = (const int*)d_in[2];
  float*       out = (float*)d_out;

  int*   perm_tbl = (int*)d_ws;
  float* wgh_tbl  = (float*)((char*)d_ws + CH * sizeof(int));
  float* part     = (float*)((char*)d_ws + 2 * CH * sizeof(int)); // 512*4*120 floats

  // d_out is re-poisoned before every launch; zero it for the atomics.
  hipMemsetAsync(d_out, 0, sizeof(float), stream);

  hipLaunchKernelGGL(topk_kernel, dim3(C_), dim3(64), 0, stream,
                     w, sel, perm_tbl, wgh_tbl);
  hipLaunchKernelGGL(gram_part_kernel, dim3(B_ * G_ * NSPLIT), dim3(256), 0, stream,
                     x, perm_tbl, part);
  hipLaunchKernelGGL(finalize_kernel, dim3(B_ * G_), dim3(128), 0, stream,
                     part, wgh_tbl, out);
}